// Round 3
// baseline (1176.649 us; speedup 1.0000x reference)
//
#include <hip/hip_runtime.h>
#include <cstdint>
#include <cstddef>

#define N_E    4096
#define NCOL   4097      // emb rows (n_e + 1)
#define DEMB   512
#define BROWS  16384     // 32 * 512 flattened key_soft rows
#define TLEN   512
#define BB     32

// ---------------- workspace layout (bytes) ----------------
#define WS_PMINV   0                          // float [2][16384] partial argmin values
#define WS_PMINI   (WS_PMINV + 2*BROWS*4)     // int   [2][16384] partial argmin indices
#define WS_KSQ     (WS_PMINI + 2*BROWS*4)     // float [16384]
#define WS_ESQ     (WS_KSQ + BROWS*4)         // float [4097] (padded to 4352)
#define WS_ENC     (WS_ESQ + 4352*4)          // int   [16384] encoding indices
#define WS_VMAX    (WS_ENC + BROWS*4)         // int   v scalar (padded to 512)
#define WS_MOVE    (WS_VMAX + 512)            // uint8 [16384][512] move bits

// ---------------- K0: squared norms ----------------
__global__ __launch_bounds__(256) void k_sq(const float* __restrict__ ks,
                                            const float* __restrict__ emb,
                                            float* __restrict__ ksq,
                                            float* __restrict__ esq) {
    const int w = threadIdx.x >> 6, lane = threadIdx.x & 63;
    const int row = blockIdx.x * 4 + w;
    if (row >= BROWS + NCOL) return;
    const float* src = (row < BROWS) ? (ks + (size_t)row * DEMB)
                                     : (emb + (size_t)(row - BROWS) * DEMB);
    float4 v1 = *(const float4*)(src + lane * 8);
    float4 v2 = *(const float4*)(src + lane * 8 + 4);
    float s = v1.x*v1.x + v1.y*v1.y + v1.z*v1.z + v1.w*v1.w
            + v2.x*v2.x + v2.y*v2.y + v2.z*v2.z + v2.w*v2.w;
    #pragma unroll
    for (int off = 32; off; off >>= 1) s += __shfl_down(s, off, 64);
    if (lane == 0) {
        if (row < BROWS) ksq[row] = s;
        else             esq[row - BROWS] = s;
    }
}

// ---------------- K1: distance GEMM + argmin + move bits ----------------
// grid 512: blockIdx = rowtile*2 + half.  half0: cols [0,2048) bits [1,2047]
//                                         half1: cols [2040,4097) bits [2048,4096]
// bit p of a row  :=  (d[p-1] > d[p])   (the "advance" decision queried at j = p-1)
__global__ __launch_bounds__(256, 2) void k_dist(const float* __restrict__ ks,
                                                 const float* __restrict__ emb,
                                                 const float* __restrict__ ksq,
                                                 const float* __restrict__ esq,
                                                 float* __restrict__ pminv,
                                                 int*   __restrict__ pmini,
                                                 uint8_t* __restrict__ movebits) {
    const int tid  = threadIdx.x;
    const int g    = tid & 31;   // col-group (8 consecutive logical cols)
    const int rg   = tid >> 5;   // row-group (8 consecutive rows)
    const int lane = tid & 63;
    const int rt   = blockIdx.x >> 1;
    const int half = blockIdx.x & 1;
    const int row0 = rt * 64;
    const int base    = half ? 2040 : 0;
    const int nchunks = half ? 9 : 8;

    __shared__ float As[32][68];    // [k][m] transposed, stride 68 (16B-aligned)
    __shared__ float Bs[32][260];   // [k][perm(n)] transposed+permuted, stride 260
    __shared__ float redv[64][33];
    __shared__ int   redi[64][33];

    float rv[8], carry[8], myksq[8];
    int   ri[8];
    #pragma unroll
    for (int i = 0; i < 8; ++i) {
        rv[i] = 3.0e38f; ri[i] = 0x7fffffff; carry[i] = 0.f;
        myksq[i] = ksq[row0 + rg * 8 + i];
    }

    for (int chunk = 0; chunk < nchunks; ++chunk) {
        const int col0 = base + chunk * 256;
        float acc[8][8];
        #pragma unroll
        for (int i = 0; i < 8; ++i)
            #pragma unroll
            for (int j = 0; j < 8; ++j) acc[i][j] = 0.f;

        const int colg = min(col0 + tid, NCOL - 1);                       // clamped emb row
        const int ph   = ((tid & 4) ? 128 : 0) + ((tid >> 3) << 2) + (tid & 3); // permuted col slot

        for (int kc = 0; kc < 16; ++kc) {
            __syncthreads();
            // stage A: 64 rows x 32 k, transposed into As[k][m]
            #pragma unroll
            for (int i2 = 0; i2 < 2; ++i2) {
                int f = tid + 256 * i2;
                int r = f >> 3, k4 = f & 7;
                float4 v = *(const float4*)(ks + (size_t)(row0 + r) * DEMB + kc * 32 + k4 * 4);
                As[k4*4+0][r] = v.x; As[k4*4+1][r] = v.y;
                As[k4*4+2][r] = v.z; As[k4*4+3][r] = v.w;
            }
            // stage B: 256 cols x 32 k, transposed + permuted
            const float* bsrc = emb + (size_t)colg * DEMB + kc * 32;
            #pragma unroll
            for (int i8 = 0; i8 < 8; ++i8) {
                float4 v = *(const float4*)(bsrc + i8 * 4);
                Bs[i8*4+0][ph] = v.x; Bs[i8*4+1][ph] = v.y;
                Bs[i8*4+2][ph] = v.z; Bs[i8*4+3][ph] = v.w;
            }
            __syncthreads();
            #pragma unroll 8
            for (int kk = 0; kk < 32; ++kk) {
                float4 a0 = *(const float4*)&As[kk][rg * 8];
                float4 a1 = *(const float4*)&As[kk][rg * 8 + 4];
                float4 b0 = *(const float4*)&Bs[kk][g * 4];
                float4 b1 = *(const float4*)&Bs[kk][128 + g * 4];
                float av[8] = {a0.x,a0.y,a0.z,a0.w,a1.x,a1.y,a1.z,a1.w};
                float bv[8] = {b0.x,b0.y,b0.z,b0.w,b1.x,b1.y,b1.z,b1.w};
                #pragma unroll
                for (int i = 0; i < 8; ++i)
                    #pragma unroll
                    for (int j = 0; j < 8; ++j)
                        acc[i][j] = fmaf(av[i], bv[j], acc[i][j]);
            }
        }

        // epilogue: dot -> distance, move-bit bytes, running argmin
        const int c0 = col0 + g * 8;
        float esqv[8];
        #pragma unroll
        for (int j = 0; j < 8; ++j) esqv[j] = esq[min(c0 + j, NCOL - 1)];
        const bool store = (half == 0) || (c0 >= 2048 && c0 <= 4088);

        #pragma unroll
        for (int i = 0; i < 8; ++i) {
            #pragma unroll
            for (int j = 0; j < 8; ++j) {
                float dd = fmaf(-2.f, acc[i][j], myksq[i] + esqv[j]);
                acc[i][j] = (c0 + j <= NCOL - 1) ? dd : 3.0e38f;
            }
            float d7       = acc[i][7];
            float fromprev = __shfl(carry[i], lane | 31, 64);   // prev chunk, lane g=31 of my row-group
            float fromleft = __shfl_up(d7, 1, 64);              // lane g-1 last col
            float left     = (g == 0) ? fromprev : fromleft;

            unsigned byte = (left > acc[i][0]) ? 1u : 0u;
            #pragma unroll
            for (int j = 1; j < 8; ++j)
                byte |= (acc[i][j-1] > acc[i][j]) ? (1u << j) : 0u;
            if (c0 == 0) byte &= 0xFEu;                          // bit 0 of row is never queried
            if (store)
                movebits[(size_t)(row0 + rg * 8 + i) * 512 + (c0 >> 3)] = (uint8_t)byte;
            carry[i] = d7;

            #pragma unroll
            for (int j = 0; j < 8; ++j) {
                float v = acc[i][j]; int idx = c0 + j;
                if (v < rv[i] || (v == rv[i] && idx < ri[i])) { rv[i] = v; ri[i] = idx; }
            }
        }
    }

    // block-level argmin reduce (lexicographic: value, then lower index)
    __syncthreads();
    #pragma unroll
    for (int i = 0; i < 8; ++i) { redv[rg*8+i][g] = rv[i]; redi[rg*8+i][g] = ri[i]; }
    __syncthreads();
    if (tid < 64) {
        float bv = redv[tid][0]; int bi = redi[tid][0];
        for (int gg = 1; gg < 32; ++gg) {
            float v = redv[tid][gg]; int idx = redi[tid][gg];
            if (v < bv || (v == bv && idx < bi)) { bv = v; bi = idx; }
        }
        pminv[half * BROWS + row0 + tid] = bv;
        pmini[half * BROWS + row0 + tid] = bi;
    }
}

// ---------------- K2: sequential neighbor scan over move bits ----------------
// one wave per batch b; lane l holds the bit-window of t-row (chunk*64 + l)
__global__ __launch_bounds__(64) void k_scan(const float* __restrict__ pminv,
                                             const int*   __restrict__ pmini,
                                             const uint8_t* __restrict__ mask,
                                             const uint8_t* __restrict__ movebits,
                                             int* __restrict__ enc,
                                             int* __restrict__ vmax) {
    const int b = blockIdx.x;
    const int lane = threadIdx.x;
    const int row0 = b * TLEN;

    // ind0 = clip(argmin(d[:,0,:]), 0, n_e-1), masked
    float v0 = pminv[row0], v1 = pminv[BROWS + row0];
    int   i0 = pmini[row0], i1 = pmini[BROWS + row0];
    int   am = (v1 < v0 || (v1 == v0 && i1 < i0)) ? i1 : i0;
    int j = min(am, N_E - 1);
    if (mask[b]) j = 0;
    const int jstart = j;

    for (int c = 0; c < 8; ++c) {
        const int t = c * 64 + lane;
        const uint32_t* rowp = (const uint32_t*)(movebits + (size_t)(row0 + t) * 512);
        // window start word, clamped so the 8-word window stays inside the
        // 128-word row (fixes OOB read when j >= 3968; q=4096 discard case
        // then reads an in-row garbage word whose bit is never used)
        const int D0a = min((j >> 5) & ~3, 120);   // uniform across lanes
        uint4 wlo = *(const uint4*)(rowp + D0a);
        uint4 whi = *(const uint4*)(rowp + D0a + 4);
        int myenc = j;
        for (int tt = 0; tt < 64; ++tt) {
            const int tglob = c * 64 + tt;
            if (tglob > 0) {
                int q  = j + 1;
                int wi = (q >> 5) - D0a;      // uniform, 0..7 for all used bits
                uint32_t sel = wi == 0 ? wlo.x : wi == 1 ? wlo.y : wi == 2 ? wlo.z :
                               wi == 3 ? wlo.w : wi == 4 ? whi.x : wi == 5 ? whi.y :
                               wi == 6 ? whi.z : whi.w;
                uint32_t word = __shfl(sel, tt, 64);   // row tglob's word
                int bit = (word >> (q & 31)) & 1;
                if (j < N_E - 1) j += bit;
            }
            if (lane == tt) myenc = j;
        }
        enc[row0 + c * 64 + lane] = myenc;
    }
    if (lane == 0) atomicMax(vmax, j - jstart);
}

// ---------------- K3: gathers, losses, outputs ----------------
__global__ __launch_bounds__(256) void k_loss(const float* __restrict__ ks,
                                              const float* __restrict__ emb,
                                              const float* __restrict__ pminv,
                                              const int*   __restrict__ pmini,
                                              const int*   __restrict__ enc,
                                              const int*   __restrict__ vmax,
                                              float* __restrict__ out) {
    const int w = threadIdx.x >> 6, lane = threadIdx.x & 63;
    const int row = blockIdx.x * 4 + w;

    float* key_hard = out;
    float* encf     = out + (size_t)BROWS * DEMB;
    float* vout     = encf + BROWS;
    float* lh       = vout + 1;
    float* ln       = lh + BROWS;

    if (blockIdx.x == 0 && threadIdx.x == 0) vout[0] = (float)(*vmax);

    const int j  = enc[row];
    const int jn = min(j + 1, N_E - 1);
    float v0 = pminv[row], v1 = pminv[BROWS + row];
    int   i0 = pmini[row], i1 = pmini[BROWS + row];
    const int mi = (v1 < v0 || (v1 == v0 && i1 < i0)) ? i1 : i0;  // unclipped argmin

    const float* ksp = ks  + (size_t)row * DEMB + lane * 8;
    const float* eh  = emb + (size_t)j   * DEMB + lane * 8;
    const float* en  = emb + (size_t)jn  * DEMB + lane * 8;
    const float* em  = emb + (size_t)mi  * DEMB + lane * 8;

    float4 ka = *(const float4*)ksp,     kb = *(const float4*)(ksp + 4);
    float4 ha = *(const float4*)eh,      hb = *(const float4*)(eh + 4);
    float4 na = *(const float4*)en,      nb = *(const float4*)(en + 4);
    float4 ma = *(const float4*)em,      mb = *(const float4*)(em + 4);

    float sh = 0.f, sn = 0.f, sm = 0.f;
    {
        float t;
        t = ka.x-ha.x; sh += t*t;  t = ka.y-ha.y; sh += t*t;
        t = ka.z-ha.z; sh += t*t;  t = ka.w-ha.w; sh += t*t;
        t = kb.x-hb.x; sh += t*t;  t = kb.y-hb.y; sh += t*t;
        t = kb.z-hb.z; sh += t*t;  t = kb.w-hb.w; sh += t*t;
        t = ka.x-na.x; sn += t*t;  t = ka.y-na.y; sn += t*t;
        t = ka.z-na.z; sn += t*t;  t = ka.w-na.w; sn += t*t;
        t = kb.x-nb.x; sn += t*t;  t = kb.y-nb.y; sn += t*t;
        t = kb.z-nb.z; sn += t*t;  t = kb.w-nb.w; sn += t*t;
        t = ka.x-ma.x; sm += t*t;  t = ka.y-ma.y; sm += t*t;
        t = ka.z-ma.z; sm += t*t;  t = ka.w-ma.w; sm += t*t;
        t = kb.x-mb.x; sm += t*t;  t = kb.y-mb.y; sm += t*t;
        t = kb.z-mb.z; sm += t*t;  t = kb.w-mb.w; sm += t*t;
    }
    #pragma unroll
    for (int off = 32; off; off >>= 1) {
        sh += __shfl_down(sh, off, 64);
        sn += __shfl_down(sn, off, 64);
        sm += __shfl_down(sm, off, 64);
    }

    // key_hard forward value = emb[enc]
    *(float4*)(key_hard + (size_t)row * DEMB + lane * 8)     = ha;
    *(float4*)(key_hard + (size_t)row * DEMB + lane * 8 + 4) = hb;

    if (lane == 0) {
        float bh = sh * 0.2f + sh;
        float bn = sn * 0.2f + sn;
        float lm = sm + sm * 0.2f;
        lh[row]   = bh - (lm < bh ? lm : 0.f);
        ln[row]   = bn - (lm < bn ? lm : 0.f);
        encf[row] = (float)j;
    }
}

// ---------------- launcher ----------------
extern "C" void kernel_launch(void* const* d_in, const int* in_sizes, int n_in,
                              void* d_out, int out_size, void* d_ws, size_t ws_size,
                              hipStream_t stream) {
    const float*   ks   = (const float*)d_in[0];
    const float*   emb  = (const float*)d_in[1];
    const uint8_t* mask = (const uint8_t*)d_in[2];
    float* out = (float*)d_out;
    uint8_t* ws = (uint8_t*)d_ws;

    float*   pminv    = (float*)(ws + WS_PMINV);
    int*     pmini    = (int*)(ws + WS_PMINI);
    float*   ksq      = (float*)(ws + WS_KSQ);
    float*   esq      = (float*)(ws + WS_ESQ);
    int*     enc      = (int*)(ws + WS_ENC);
    int*     vmax     = (int*)(ws + WS_VMAX);
    uint8_t* movebits = ws + WS_MOVE;

    hipMemsetAsync(vmax, 0, 4, stream);
    k_sq  <<<(BROWS + NCOL + 3) / 4, 256, 0, stream>>>(ks, emb, ksq, esq);
    k_dist<<<512, 256, 0, stream>>>(ks, emb, ksq, esq, pminv, pmini, movebits);
    k_scan<<<BB, 64, 0, stream>>>(pminv, pmini, mask, movebits, enc, vmax);
    k_loss<<<BROWS / 4, 256, 0, stream>>>(ks, emb, pminv, pmini, enc, vmax, out);
}

// Round 5
// 619.376 us; speedup vs baseline: 1.8997x; 1.8997x over previous
//
#include <hip/hip_runtime.h>
#include <cstdint>
#include <cstddef>

#define N_E    4096
#define NCOL   4097      // emb rows (n_e + 1)
#define DEMB   512
#define BROWS  16384     // 32 * 512 flattened key_soft rows
#define TLEN   512
#define BB     32
#define NTM    128       // m tiles (16384/128)
#define NTN    33        // n tiles (ceil(4097/128))
#define NWG    (NTM*NTN) // 4224, divisible by 8 -> XCD swizzle bijective

typedef __attribute__((ext_vector_type(8))) short short8;
typedef __attribute__((ext_vector_type(4))) float f4;

// ---------------- workspace layout (bytes, ~17.3 MB total) ----------------
#define WS_KSQ   0                            // float [16384]
#define WS_ESQ   (WS_KSQ + BROWS*4)           // float [4160]
#define WS_PMVB  (WS_ESQ + 4160*4)            // float [33][16384] per-block argmin val
#define WS_PMIB  (WS_PMVB + NTN*BROWS*4)      // int   [33][16384] per-block argmin idx
#define WS_DFB   (WS_PMIB + NTN*BROWS*4)      // float [33][16384] d at col nt*128
#define WS_DLB   (WS_DFB + NTN*BROWS*4)       // float [33][16384] d at col nt*128+127
#define WS_PMVF  (WS_DLB + NTN*BROWS*4)       // float [16384]
#define WS_PMIF  (WS_PMVF + BROWS*4)          // int   [16384]
#define WS_ENC   (WS_PMIF + BROWS*4)          // int   [16384]
#define WS_VMAX  (WS_ENC + BROWS*4)           // int (padded 512)
#define WS_MOVE  (WS_VMAX + 512)              // uint8 [16384][512]

// packed bf16(RNE) pair: h = {bf16(x1),bf16(x0)}, l = bf16 pair of residuals
__device__ __forceinline__ void cvtpair(float x0, float x1, unsigned int& h, unsigned int& l) {
    asm("v_cvt_pk_bf16_f32 %0, %1, %2" : "=v"(h) : "v"(x0), "v"(x1));
    float h0 = __uint_as_float(h << 16);
    float h1 = __uint_as_float(h & 0xFFFF0000u);
    float l0 = x0 - h0, l1 = x1 - h1;
    asm("v_cvt_pk_bf16_f32 %0, %1, %2" : "=v"(l) : "v"(l0), "v"(l1));
}

// ---------------- K0: squared norms (round-2 proven form) ----------------
__global__ __launch_bounds__(256) void k_sq(const float* __restrict__ ks,
                                            const float* __restrict__ emb,
                                            float* __restrict__ ksq,
                                            float* __restrict__ esq) {
    const int w = threadIdx.x >> 6, lane = threadIdx.x & 63;
    const int row = blockIdx.x * 4 + w;
    if (row >= BROWS + NCOL) return;
    const float* src = (row < BROWS) ? (ks + (size_t)row * DEMB)
                                     : (emb + (size_t)(row - BROWS) * DEMB);
    float4 v1 = *(const float4*)(src + lane * 8);
    float4 v2 = *(const float4*)(src + lane * 8 + 4);
    float s = v1.x*v1.x + v1.y*v1.y + v1.z*v1.z + v1.w*v1.w
            + v2.x*v2.x + v2.y*v2.y + v2.z*v2.z + v2.w*v2.w;
    #pragma unroll
    for (int off = 32; off; off >>= 1) s += __shfl_down(s, off, 64);
    if (lane == 0) {
        if (row < BROWS) ksq[row] = s;
        else             esq[row - BROWS] = s;
    }
}

// ---------------- K1: bf16-3-split MFMA distance GEMM ----------------
// dot = Ahi*Bhi + Ahi*Blo + Alo*Bhi (fp32 MFMA accumulate, 16x16x32).
// 128x128 tile, 4 waves (2m x 2n), dbuf LDS, on-the-fly hi/lo split of BOTH operands.
__global__ __launch_bounds__(256, 2) void k_dist(const float* __restrict__ ks,
                                                 const float* __restrict__ emb,
                                                 const float* __restrict__ ksq,
                                                 const float* __restrict__ esq,
                                                 float* __restrict__ pminvB,
                                                 int*   __restrict__ pminiB,
                                                 float* __restrict__ dfB,
                                                 float* __restrict__ dlB,
                                                 unsigned short* __restrict__ mb16) {
    const int t   = threadIdx.x;
    const int bid = blockIdx.x;
    const int swz = (bid & 7) * (NWG / 8) + (bid >> 3);   // XCD-chunked swizzle
    const int mt  = swz / NTN, nt = swz % NTN;
    const int row0 = mt * 128, n0 = nt * 128;

    __shared__ short lds[2][4][128 * 40];  // [buf][Ahi,Alo,Bhi,Blo][(row|col) x padded-k]

    // staging: thread t -> row/col sr, k-half sh (16 elems per tile)
    const int sr = t >> 1, sh = t & 1;
    const float* ap = ks + (size_t)(row0 + sr) * DEMB + sh * 16;
    const int bc = min(n0 + sr, NCOL - 1);
    const float* bp = emb + (size_t)bc * DEMB + sh * 16;
    const int wA = sr * 40 + sh * 16;

    // wave / fragment geometry (A: row=lane&15, k=(lane>>4)*8+j ; B: col=lane&15)
    const int w = t >> 6, lane = t & 63;
    const int wm = w >> 1, wn = w & 1;
    const int lq = lane >> 4, lr = lane & 15;
    int aoff[4], boff[4];
    #pragma unroll
    for (int i = 0; i < 4; ++i) aoff[i] = (wm*64 + i*16 + lr)*40 + lq*8;
    #pragma unroll
    for (int j = 0; j < 4; ++j) boff[j] = (wn*64 + j*16 + lr)*40 + lq*8;

    f4 acc[4][4];
    const f4 fz = {0.f, 0.f, 0.f, 0.f};
    #pragma unroll
    for (int i = 0; i < 4; ++i)
        #pragma unroll
        for (int j = 0; j < 4; ++j) acc[i][j] = fz;

    float4 la0, la1, la2, la3, lb0, lb1, lb2, lb3;

    auto do_loads = [&](int s) {
        const float* p = ap + s * 32;
        la0 = *(const float4*)p;       la1 = *(const float4*)(p + 4);
        la2 = *(const float4*)(p + 8); la3 = *(const float4*)(p + 12);
        const float* q = bp + s * 32;
        lb0 = *(const float4*)q;       lb1 = *(const float4*)(q + 4);
        lb2 = *(const float4*)(q + 8); lb3 = *(const float4*)(q + 12);
    };
    auto do_cw = [&](int cb) {
        unsigned int h0,h1,h2,h3,h4,h5,h6,h7, g0,g1,g2,g3,g4,g5,g6,g7;
        cvtpair(la0.x, la0.y, h0, g0); cvtpair(la0.z, la0.w, h1, g1);
        cvtpair(la1.x, la1.y, h2, g2); cvtpair(la1.z, la1.w, h3, g3);
        cvtpair(la2.x, la2.y, h4, g4); cvtpair(la2.z, la2.w, h5, g5);
        cvtpair(la3.x, la3.y, h6, g6); cvtpair(la3.z, la3.w, h7, g7);
        *(uint4*)(&lds[cb][0][wA])     = (uint4){h0,h1,h2,h3};
        *(uint4*)(&lds[cb][0][wA + 8]) = (uint4){h4,h5,h6,h7};
        *(uint4*)(&lds[cb][1][wA])     = (uint4){g0,g1,g2,g3};
        *(uint4*)(&lds[cb][1][wA + 8]) = (uint4){g4,g5,g6,g7};
        cvtpair(lb0.x, lb0.y, h0, g0); cvtpair(lb0.z, lb0.w, h1, g1);
        cvtpair(lb1.x, lb1.y, h2, g2); cvtpair(lb1.z, lb1.w, h3, g3);
        cvtpair(lb2.x, lb2.y, h4, g4); cvtpair(lb2.z, lb2.w, h5, g5);
        cvtpair(lb3.x, lb3.y, h6, g6); cvtpair(lb3.z, lb3.w, h7, g7);
        *(uint4*)(&lds[cb][2][wA])     = (uint4){h0,h1,h2,h3};
        *(uint4*)(&lds[cb][2][wA + 8]) = (uint4){h4,h5,h6,h7};
        *(uint4*)(&lds[cb][3][wA])     = (uint4){g0,g1,g2,g3};
        *(uint4*)(&lds[cb][3][wA + 8]) = (uint4){g4,g5,g6,g7};
    };
    auto do_mm = [&](int cb) {
        short8 fAh[4], fAl[4], fBh[4], fBl[4];
        #pragma unroll
        for (int i = 0; i < 4; ++i) {
            fAh[i] = *(const short8*)(&lds[cb][0][aoff[i]]);
            fAl[i] = *(const short8*)(&lds[cb][1][aoff[i]]);
        }
        #pragma unroll
        for (int j = 0; j < 4; ++j) {
            fBh[j] = *(const short8*)(&lds[cb][2][boff[j]]);
            fBl[j] = *(const short8*)(&lds[cb][3][boff[j]]);
        }
        #pragma unroll
        for (int i = 0; i < 4; ++i)
            #pragma unroll
            for (int j = 0; j < 4; ++j)
                acc[i][j] = __builtin_amdgcn_mfma_f32_16x16x32_bf16(fAh[i], fBh[j], acc[i][j], 0, 0, 0);
        #pragma unroll
        for (int i = 0; i < 4; ++i)
            #pragma unroll
            for (int j = 0; j < 4; ++j)
                acc[i][j] = __builtin_amdgcn_mfma_f32_16x16x32_bf16(fAh[i], fBl[j], acc[i][j], 0, 0, 0);
        #pragma unroll
        for (int i = 0; i < 4; ++i)
            #pragma unroll
            for (int j = 0; j < 4; ++j)
                acc[i][j] = __builtin_amdgcn_mfma_f32_16x16x32_bf16(fAl[i], fBh[j], acc[i][j], 0, 0, 0);
    };

    // main loop: 16 k-tiles, explicit buffer alternation (literal indices)
    do_loads(0); do_cw(0); __syncthreads();
    for (int s2 = 0; s2 < 7; ++s2) {
        do_loads(2*s2 + 1); do_mm(0); do_cw(1); __syncthreads();
        do_loads(2*s2 + 2); do_mm(1); do_cw(0); __syncthreads();
    }
    do_loads(15); do_mm(0); do_cw(1); __syncthreads();
    do_mm(1);
    __syncthreads();   // all waves done reading LDS -> safe to reuse as scratch

    // LDS scratch (reuses the staging buffer)
    float* sv0 = (float*)&lds[0][0][0];   // [128][2] wave argmin val
    int*   si0 = (int*)(sv0 + 256);       // [128][2] wave argmin idx
    float* sdl = (float*)(si0 + 256);     // [128] wn0 d at col n0+63
    float* sdf = sdl + 128;               // [128] wn1 d at col n0+64
    float* sd0 = sdf + 128;               // [128] wn0 d at col n0     (block dfirst)
    float* sd1 = sd0 + 128;               // [128] wn1 d at col n0+127 (block dlast)

    // ---------------- epilogue: d, movebits, argmin ----------------
    const int colC = n0 + wn * 64;
    float esqv[4];
    #pragma unroll
    for (int j = 0; j < 4; ++j) esqv[j] = esq[min(colC + j*16 + lr, NCOL - 1)];

    #pragma unroll
    for (int i = 0; i < 4; ++i) {
        #pragma unroll
        for (int r2 = 0; r2 < 4; ++r2) {
            const int rowl = wm*64 + i*16 + lq*4 + r2;   // C/D: row=(lane>>4)*4+reg
            const int R = row0 + rowl;
            const float kq = ksq[R];
            float dj[4];
            #pragma unroll
            for (int j = 0; j < 4; ++j) {
                float dd = fmaf(-2.f, acc[i][j][r2], kq + esqv[j]);
                dj[j] = (colC + j*16 + lr <= NCOL - 1) ? dd : 3.0e38f;
            }
            // wave-level argmin over its 64 cols (lexicographic)
            float bv = dj[0]; int bi = colC + lr;
            #pragma unroll
            for (int j = 1; j < 4; ++j) {
                int c = colC + j*16 + lr;
                if (dj[j] < bv || (dj[j] == bv && c < bi)) { bv = dj[j]; bi = c; }
            }
            #pragma unroll
            for (int off = 1; off < 16; off <<= 1) {
                float ov = __shfl_xor(bv, off, 64); int oi = __shfl_xor(bi, off, 64);
                if (ov < bv || (ov == bv && oi < bi)) { bv = ov; bi = oi; }
            }
            if (lr == 0) {
                sv0[rowl*2 + wn] = bv; si0[rowl*2 + wn] = bi;
                if (wn == 1) sdf[rowl] = dj[0];
                else         sd0[rowl] = dj[0];
            }
            if (lr == 15) {
                if (wn == 0) sdl[rowl] = dj[3];
                else         sd1[rowl] = dj[3];
            }
            // move bits: bit p = (d[p-1] > d[p]); p = wave's first col handled elsewhere
            #pragma unroll
            for (int j = 0; j < 4; ++j) {
                float left = __shfl_up(dj[j], 1, 64);
                if (j > 0) {
                    float ph = __shfl(dj[j-1], (lane & 48) | 15, 64);
                    if (lr == 0) left = ph;
                }
                bool pred = (lr == 0 && j == 0) ? false : (left > dj[j]);
                unsigned long long bal = __ballot(pred);
                const int Cb = colC + j * 16;
                if (lr == 0 && Cb < 4096)
                    mb16[(size_t)R*256 + (Cb >> 4)] = (unsigned short)((bal >> (lq*16)) & 0xFFFFull);
            }
        }
    }
    __syncthreads();
    if (t < 128) {
        const int R = row0 + t;
        float v0 = sv0[t*2], v1 = sv0[t*2+1];
        int   i0 = si0[t*2], i1 = si0[t*2+1];
        const bool sel = (v1 < v0 || (v1 == v0 && i1 < i0));
        pminvB[nt*BROWS + R] = sel ? v1 : v0;
        pminiB[nt*BROWS + R] = sel ? i1 : i0;
        dfB[nt*BROWS + R] = sd0[t];
        dlB[nt*BROWS + R] = sd1[t];
        if (nt < 32 && sdl[t] > sdf[t]) {            // in-block seam bit p = n0+64
            uint8_t* mbyte = (uint8_t*)mb16 + (size_t)R*512 + 16*nt + 8;
            *mbyte = (uint8_t)(*mbyte | 1u);
        }
    }
}

// ---------------- K2: 33-block argmin reduce + 128-col seam bits ----------
__global__ __launch_bounds__(256) void k_bnd(const float* __restrict__ pminvB,
                                             const int*   __restrict__ pminiB,
                                             const float* __restrict__ dfB,
                                             const float* __restrict__ dlB,
                                             float* __restrict__ pminvF,
                                             int*   __restrict__ pminiF,
                                             uint8_t* __restrict__ movebits) {
    const int w = threadIdx.x >> 6, lane = threadIdx.x & 63;
    const int m = blockIdx.x * 4 + w;
    float bv = 3.0e38f; int bi = 0x7fffffff;
    if (lane < NTN) { bv = pminvB[lane*BROWS + m]; bi = pminiB[lane*BROWS + m]; }
    #pragma unroll
    for (int off = 1; off < 64; off <<= 1) {
        float ov = __shfl_xor(bv, off, 64); int oi = __shfl_xor(bi, off, 64);
        if (ov < bv || (ov == bv && oi < bi)) { bv = ov; bi = oi; }
    }
    if (lane == 0) { pminvF[m] = bv; pminiF[m] = bi; }
    if (lane >= 1 && lane < 32) {   // bit p = 128*lane
        bool b = dlB[(lane-1)*BROWS + m] > dfB[lane*BROWS + m];
        if (b) {
            uint8_t* p = movebits + (size_t)m * 512 + 16 * lane;
            *p = (uint8_t)(*p | 1u);
        }
    }
}

// ---------------- K3: sequential neighbor scan over move bits ----------------
__global__ __launch_bounds__(64) void k_scan(const int* __restrict__ pminiF,
                                             const uint8_t* __restrict__ mask,
                                             const uint8_t* __restrict__ movebits,
                                             int* __restrict__ enc,
                                             int* __restrict__ vmax) {
    const int b = blockIdx.x;
    const int lane = threadIdx.x;
    const int row0 = b * TLEN;

    int j = min(pminiF[row0], N_E - 1);
    if (mask[b]) j = 0;
    const int jstart = j;

    for (int c = 0; c < 8; ++c) {
        const int t = c * 64 + lane;
        const uint32_t* rowp = (const uint32_t*)(movebits + (size_t)(row0 + t) * 512);
        const int D0a = min((j >> 5) & ~3, 120);   // uniform, window in-row
        uint4 wlo = *(const uint4*)(rowp + D0a);
        uint4 whi = *(const uint4*)(rowp + D0a + 4);
        int myenc = j;
        for (int tt = 0; tt < 64; ++tt) {
            const int tglob = c * 64 + tt;
            if (tglob > 0) {
                int q  = j + 1;
                int wi = (q >> 5) - D0a;
                uint32_t sel = wi == 0 ? wlo.x : wi == 1 ? wlo.y : wi == 2 ? wlo.z :
                               wi == 3 ? wlo.w : wi == 4 ? whi.x : wi == 5 ? whi.y :
                               wi == 6 ? whi.z : whi.w;
                uint32_t word = __shfl(sel, tt, 64);
                int bit = (word >> (q & 31)) & 1;
                if (j < N_E - 1) j += bit;
            }
            if (lane == tt) myenc = j;
        }
        enc[row0 + c * 64 + lane] = myenc;
    }
    if (lane == 0) atomicMax(vmax, j - jstart);
}

// ---------------- K4: gathers, losses, outputs ----------------
__global__ __launch_bounds__(256) void k_loss(const float* __restrict__ ks,
                                              const float* __restrict__ emb,
                                              const int*   __restrict__ pminiF,
                                              const int*   __restrict__ enc,
                                              const int*   __restrict__ vmax,
                                              float* __restrict__ out) {
    const int w = threadIdx.x >> 6, lane = threadIdx.x & 63;
    const int row = blockIdx.x * 4 + w;

    float* key_hard = out;
    float* encf     = out + (size_t)BROWS * DEMB;
    float* vout     = encf + BROWS;
    float* lh       = vout + 1;
    float* ln       = lh + BROWS;

    if (blockIdx.x == 0 && threadIdx.x == 0) vout[0] = (float)(*vmax);

    const int j  = enc[row];
    const int jn = min(j + 1, N_E - 1);
    const int mi = pminiF[row];   // unclipped argmin

    const float* ksp = ks  + (size_t)row * DEMB + lane * 8;
    const float* eh  = emb + (size_t)j   * DEMB + lane * 8;
    const float* en  = emb + (size_t)jn  * DEMB + lane * 8;
    const float* em  = emb + (size_t)mi  * DEMB + lane * 8;

    float4 ka = *(const float4*)ksp,     kb = *(const float4*)(ksp + 4);
    float4 ha = *(const float4*)eh,      hb = *(const float4*)(eh + 4);
    float4 na = *(const float4*)en,      nb = *(const float4*)(en + 4);
    float4 ma = *(const float4*)em,      mb = *(const float4*)(em + 4);

    float sh = 0.f, sn = 0.f, sm = 0.f;
    {
        float t;
        t = ka.x-ha.x; sh += t*t;  t = ka.y-ha.y; sh += t*t;
        t = ka.z-ha.z; sh += t*t;  t = ka.w-ha.w; sh += t*t;
        t = kb.x-hb.x; sh += t*t;  t = kb.y-hb.y; sh += t*t;
        t = kb.z-hb.z; sh += t*t;  t = kb.w-hb.w; sh += t*t;
        t = ka.x-na.x; sn += t*t;  t = ka.y-na.y; sn += t*t;
        t = ka.z-na.z; sn += t*t;  t = ka.w-na.w; sn += t*t;
        t = kb.x-nb.x; sn += t*t;  t = kb.y-nb.y; sn += t*t;
        t = kb.z-nb.z; sn += t*t;  t = kb.w-nb.w; sn += t*t;
        t = ka.x-ma.x; sm += t*t;  t = ka.y-ma.y; sm += t*t;
        t = ka.z-ma.z; sm += t*t;  t = ka.w-ma.w; sm += t*t;
        t = kb.x-mb.x; sm += t*t;  t = kb.y-mb.y; sm += t*t;
        t = kb.z-mb.z; sm += t*t;  t = kb.w-mb.w; sm += t*t;
    }
    #pragma unroll
    for (int off = 32; off; off >>= 1) {
        sh += __shfl_down(sh, off, 64);
        sn += __shfl_down(sn, off, 64);
        sm += __shfl_down(sm, off, 64);
    }

    *(float4*)(key_hard + (size_t)row * DEMB + lane * 8)     = ha;
    *(float4*)(key_hard + (size_t)row * DEMB + lane * 8 + 4) = hb;

    if (lane == 0) {
        float bh = sh * 0.2f + sh;
        float bn = sn * 0.2f + sn;
        float lm = sm + sm * 0.2f;
        lh[row]   = bh - (lm < bh ? lm : 0.f);
        ln[row]   = bn - (lm < bn ? lm : 0.f);
        encf[row] = (float)j;
    }
}

// ---------------- launcher ----------------
extern "C" void kernel_launch(void* const* d_in, const int* in_sizes, int n_in,
                              void* d_out, int out_size, void* d_ws, size_t ws_size,
                              hipStream_t stream) {
    const float*   ks   = (const float*)d_in[0];
    const float*   emb  = (const float*)d_in[1];
    const uint8_t* mask = (const uint8_t*)d_in[2];
    float* out = (float*)d_out;
    uint8_t* ws = (uint8_t*)d_ws;

    float* ksq    = (float*)(ws + WS_KSQ);
    float* esq    = (float*)(ws + WS_ESQ);
    float* pminvB = (float*)(ws + WS_PMVB);
    int*   pminiB = (int*)(ws + WS_PMIB);
    float* dfB    = (float*)(ws + WS_DFB);
    float* dlB    = (float*)(ws + WS_DLB);
    float* pminvF = (float*)(ws + WS_PMVF);
    int*   pminiF = (int*)(ws + WS_PMIF);
    int*   enc    = (int*)(ws + WS_ENC);
    int*   vmax   = (int*)(ws + WS_VMAX);
    uint8_t* movebits = ws + WS_MOVE;

    hipMemsetAsync(vmax, 0, 4, stream);
    k_sq  <<<(BROWS + NCOL + 3) / 4, 256, 0, stream>>>(ks, emb, ksq, esq);
    k_dist<<<NWG, 256, 0, stream>>>(ks, emb, ksq, esq, pminvB, pminiB,
                                    dfB, dlB, (unsigned short*)movebits);
    k_bnd <<<BROWS / 4, 256, 0, stream>>>(pminvB, pminiB, dfB, dlB, pminvF, pminiF, movebits);
    k_scan<<<BB, 64, 0, stream>>>(pminiF, mask, movebits, enc, vmax);
    k_loss<<<BROWS / 4, 256, 0, stream>>>(ks, emb, pminiF, enc, vmax, out);
}